// Round 1
// baseline (225.556 us; speedup 1.0000x reference)
//
#include <hip/hip_runtime.h>
#include <hip/hip_bf16.h>

// Problem constants (fixed shapes)
#define T_SEQ 1024
#define NBATCH 8
#define NHEAD 12
#define HD 64
#define CDIM 768
#define C3 2304
#define ATT_SCALE 0.125f   // 1/sqrt(64)

typedef __attribute__((ext_vector_type(8))) __bf16 bf16x8;
typedef __attribute__((ext_vector_type(4))) __bf16 bf16x4;
typedef __attribute__((ext_vector_type(4))) float  f32x4;

__device__ __forceinline__ f32x4 mfma_bf16(bf16x8 a, bf16x8 b, f32x4 c) {
    return __builtin_amdgcn_mfma_f32_16x16x32_bf16(a, b, c, 0, 0, 0);
}

// async global->LDS, 16B per lane; LDS dest must be wave-uniform base (+lane*16 implicit)
__device__ __forceinline__ void gload16(const void* g, void* l) {
    __builtin_amdgcn_global_load_lds(
        (const __attribute__((address_space(1))) unsigned int*)g,
        (__attribute__((address_space(3))) unsigned int*)l, 16, 0, 0);
}

// ---------------- f32 -> bf16 convert (vectorized) ----------------
__global__ __launch_bounds__(256) void cvt_f32_bf16(const float* __restrict__ in,
                                                    __bf16* __restrict__ out, int n4) {
    int i = blockIdx.x * 256 + threadIdx.x;
    if (i < n4) {
        float4 v = ((const float4*)in)[i];
        bf16x4 o = { (__bf16)v.x, (__bf16)v.y, (__bf16)v.z, (__bf16)v.w };
        ((bf16x4*)out)[i] = o;
    }
}

// ---------------- transpose + convert: W [R][C] f32 -> Wt [C][R] bf16 ----------------
__global__ __launch_bounds__(256) void transpose_cvt(const float* __restrict__ W,
                                                     __bf16* __restrict__ Wt,
                                                     int R, int C) {
    __shared__ float tile[32][33];
    const int c0 = blockIdx.x * 32, r0 = blockIdx.y * 32;
    const int tc = threadIdx.x & 31, tr = threadIdx.x >> 5;   // tr in 0..7
#pragma unroll
    for (int i = 0; i < 4; ++i)
        tile[tr + i * 8][tc] = W[(size_t)(r0 + tr + i * 8) * C + c0 + tc];
    __syncthreads();
#pragma unroll
    for (int i = 0; i < 4; ++i)
        Wt[(size_t)(c0 + tr + i * 8) * R + r0 + tc] = (__bf16)tile[tc][tr + i * 8];
}

// ---------------- GEMM: C[M][N] = A[M][K] @ Bt[N][K]^T + bias ----------------
// 128x128 tile, BK=32, 4 waves (2x2), each wave 64x64 via 4x4 16x16x32 MFMA frags.
template<int OUT_BF16>
__global__ __launch_bounds__(256) void gemm_bt(const __bf16* __restrict__ A,
                                               const __bf16* __restrict__ Bt,
                                               const float* __restrict__ bias,
                                               void* __restrict__ Cout,
                                               int M, int N, int K) {
    __shared__ __align__(16) __bf16 sA[128 * 32];
    __shared__ __align__(16) __bf16 sB[128 * 32];
    const int t = threadIdx.x, l = t & 63, w = t >> 6;
    const int lr = l & 15, lk = l >> 4;
    const int wr = w >> 1, wc = w & 1;
    const int m0 = blockIdx.y * 128, n0 = blockIdx.x * 128;

    f32x4 acc[4][4];
#pragma unroll
    for (int m = 0; m < 4; ++m)
#pragma unroll
        for (int n = 0; n < 4; ++n) acc[m][n] = f32x4{0.f, 0.f, 0.f, 0.f};

    for (int k0 = 0; k0 < K; k0 += 32) {
        // stage A,B tiles (each 128x32 bf16 = 8KB = 512 x 16B chunks; 256 thr x 2)
#pragma unroll
        for (int i = 0; i < 2; ++i) {
            int idx = i * 256 + t;
            int r = idx >> 2, c = (idx & 3) << 3;
            gload16(A + (size_t)(m0 + r) * K + k0 + c, (char*)sA + (i * 256 + w * 64) * 16);
            gload16(Bt + (size_t)(n0 + r) * K + k0 + c, (char*)sB + (i * 256 + w * 64) * 16);
        }
        __syncthreads();   // drains vmcnt for global_load_lds

        bf16x8 af[4], bg[4];
#pragma unroll
        for (int m = 0; m < 4; ++m)
            af[m] = *(const bf16x8*)(sA + (wr * 64 + m * 16 + lr) * 32 + lk * 8);
#pragma unroll
        for (int n = 0; n < 4; ++n)
            bg[n] = *(const bf16x8*)(sB + (wc * 64 + n * 16 + lr) * 32 + lk * 8);
#pragma unroll
        for (int m = 0; m < 4; ++m)
#pragma unroll
            for (int n = 0; n < 4; ++n)
                acc[m][n] = mfma_bf16(af[m], bg[n], acc[m][n]);
        __syncthreads();
    }

    // epilogue: C row=(lk*4+j), col=lr within each 16x16 frag (m89-verified layout)
#pragma unroll
    for (int n = 0; n < 4; ++n) {
        int col = n0 + wc * 64 + n * 16 + lr;
        float bv = bias[col];
#pragma unroll
        for (int m = 0; m < 4; ++m) {
            int row0 = m0 + wr * 64 + m * 16 + lk * 4;
#pragma unroll
            for (int j = 0; j < 4; ++j) {
                float v = acc[m][n][j] + bv;
                if (OUT_BF16)
                    ((__bf16*)Cout)[(size_t)(row0 + j) * N + col] = (__bf16)v;
                else
                    ((float*)Cout)[(size_t)(row0 + j) * N + col] = v;
            }
        }
    }
}

// ---------------- causal flash attention ----------------
// block = 256 thr (4 waves); block handles one (b, h, 64 q-rows); wave owns 16 q-rows.
// KV tiles of 64 keys. K fragments read direct from global (L2-resident);
// V staged transposed in LDS (sV[d][key]) for the PV B-operand.
__global__ __launch_bounds__(256) void attn_fwd(const __bf16* __restrict__ qkv,
                                                __bf16* __restrict__ y) {
    const int t = threadIdx.x, l = t & 63, w = t >> 6;
    const int lr = l & 15, lk = l >> 4;
    const int bid = blockIdx.x;
    const int qt = bid & 15;                 // T/64 = 16 q-tiles
    const int h = (bid >> 4) % NHEAD;
    const int b = bid / (16 * NHEAD);
    const int q0 = qt * 64;

    __shared__ __align__(16) __bf16 sV[64][72];       // [d][key], pad 72 -> 2-way reads
    __shared__ __align__(16) __bf16 sP[4][16][72];    // per-wave P tile [q][key]

    // Q fragments (held in regs across all KV tiles)
    const size_t rowQ = ((size_t)(b * T_SEQ + q0 + w * 16 + lr)) * C3 + h * HD;
    bf16x8 qa0 = *(const bf16x8*)(qkv + rowQ + lk * 8);
    bf16x8 qa1 = *(const bf16x8*)(qkv + rowQ + 32 + lk * 8);

    f32x4 acc_o[4];
#pragma unroll
    for (int fd = 0; fd < 4; ++fd) acc_o[fd] = f32x4{0.f, 0.f, 0.f, 0.f};
    float mrow[4] = {-1e30f, -1e30f, -1e30f, -1e30f};
    float lsum[4] = {0.f, 0.f, 0.f, 0.f};

    const size_t baseK = (size_t)b * T_SEQ * C3 + CDIM + h * HD;
    const size_t baseV = (size_t)b * T_SEQ * C3 + 2 * CDIM + h * HD;

    const int kv_end = q0 + 64;
    for (int kv0 = 0; kv0 < kv_end; kv0 += 64) {
        // V tile -> regs (coalesced 16B/lane)
        bf16x8 vreg[2]; int vkey[2], vc[2];
#pragma unroll
        for (int i = 0; i < 2; ++i) {
            int idx = i * 256 + t;
            vkey[i] = idx >> 3; vc[i] = (idx & 7) << 3;
            vreg[i] = *(const bf16x8*)(qkv + baseV + (size_t)(kv0 + vkey[i]) * C3 + vc[i]);
        }
        // S = Q K^T : 4 key-frags x 2 k-steps
        f32x4 s[4];
#pragma unroll
        for (int fc = 0; fc < 4; ++fc) {
            const __bf16* kp = qkv + baseK + (size_t)(kv0 + fc * 16 + lr) * C3 + lk * 8;
            bf16x8 kb0 = *(const bf16x8*)kp;
            bf16x8 kb1 = *(const bf16x8*)(kp + 32);
            f32x4 z = f32x4{0.f, 0.f, 0.f, 0.f};
            z = mfma_bf16(qa0, kb0, z);
            z = mfma_bf16(qa1, kb1, z);
            s[fc] = z;
        }
        __syncthreads();                       // prev-tile PV done -> safe to overwrite sV
#pragma unroll
        for (int i = 0; i < 2; ++i)
#pragma unroll
            for (int e = 0; e < 8; ++e)
                sV[vc[i] + e][vkey[i]] = vreg[i][e];

        // online softmax (wave-parallel, 16-lane group shuffles)
        float ps[4][4];
        const int qrow = q0 + w * 16 + lk * 4;
#pragma unroll
        for (int fc = 0; fc < 4; ++fc) {
            int key = kv0 + fc * 16 + lr;
#pragma unroll
            for (int j = 0; j < 4; ++j)
                ps[fc][j] = (key <= qrow + j) ? s[fc][j] * ATT_SCALE : -1e30f;
        }
#pragma unroll
        for (int j = 0; j < 4; ++j) {
            float mt = fmaxf(fmaxf(ps[0][j], ps[1][j]), fmaxf(ps[2][j], ps[3][j]));
#pragma unroll
            for (int off = 1; off < 16; off <<= 1)
                mt = fmaxf(mt, __shfl_xor(mt, off, 64));
            float mn = fmaxf(mrow[j], mt);
            float corr = __expf(mrow[j] - mn);
            mrow[j] = mn;
            float rsum = 0.f;
#pragma unroll
            for (int fc = 0; fc < 4; ++fc) {
                float p = __expf(ps[fc][j] - mn);
                ps[fc][j] = p;
                rsum += p;
            }
#pragma unroll
            for (int off = 1; off < 16; off <<= 1)
                rsum += __shfl_xor(rsum, off, 64);
            lsum[j] = lsum[j] * corr + rsum;
#pragma unroll
            for (int fd = 0; fd < 4; ++fd) acc_o[fd][j] *= corr;
        }
        // P -> LDS (bf16) in A-fragment-readable layout
#pragma unroll
        for (int fc = 0; fc < 4; ++fc)
#pragma unroll
            for (int j = 0; j < 4; ++j)
                sP[w][lk * 4 + j][fc * 16 + lr] = (__bf16)ps[fc][j];
        __syncthreads();                       // sV writes visible
        // O += P V
#pragma unroll
        for (int ks = 0; ks < 2; ++ks) {
            bf16x8 pa = *(const bf16x8*)(&sP[w][lr][ks * 32 + lk * 8]);
#pragma unroll
            for (int fd = 0; fd < 4; ++fd) {
                bf16x8 vb = *(const bf16x8*)(&sV[fd * 16 + lr][ks * 32 + lk * 8]);
                acc_o[fd] = mfma_bf16(pa, vb, acc_o[fd]);
            }
        }
    }

    // epilogue: y[b*T+t][h*64+d] = O/lsum  (bf16, [8192][768])
    float linv[4];
#pragma unroll
    for (int j = 0; j < 4; ++j) linv[j] = 1.f / lsum[j];
    const size_t yrow0 = (size_t)(b * T_SEQ + q0 + w * 16 + lk * 4);
#pragma unroll
    for (int fd = 0; fd < 4; ++fd) {
        int col = h * HD + fd * 16 + lr;
#pragma unroll
        for (int j = 0; j < 4; ++j)
            y[(yrow0 + j) * CDIM + col] = (__bf16)(acc_o[fd][j] * linv[j]);
    }
}

// ---------------- launch ----------------
extern "C" void kernel_launch(void* const* d_in, const int* in_sizes, int n_in,
                              void* d_out, int out_size, void* d_ws, size_t ws_size,
                              hipStream_t stream) {
    const float* x      = (const float*)d_in[0];
    const float* W_attn = (const float*)d_in[1];
    const float* b_attn = (const float*)d_in[2];
    const float* W_proj = (const float*)d_in[3];
    const float* b_proj = (const float*)d_in[4];

    // workspace layout (bf16), ~64.5 MB total
    __bf16* xb  = (__bf16*)d_ws;                       // [8192][768]
    __bf16* Wat = xb  + (size_t)8192 * 768;            // [2304][768]  (W_attn^T)
    __bf16* Wpt = Wat + (size_t)2304 * 768;            // [768][768]   (W_proj^T)
    __bf16* qkv = Wpt + (size_t)768 * 768;             // [8192][2304]
    __bf16* yb  = qkv + (size_t)8192 * 2304;           // [8192][768]

    cvt_f32_bf16<<<6144, 256, 0, stream>>>(x, xb, (8192 * 768) / 4);
    transpose_cvt<<<dim3(72, 24), 256, 0, stream>>>(W_attn, Wat, 768, 2304);
    transpose_cvt<<<dim3(24, 24), 256, 0, stream>>>(W_proj, Wpt, 768, 768);

    gemm_bt<1><<<dim3(18, 64), 256, 0, stream>>>(xb, Wat, b_attn, (void*)qkv, 8192, 2304, 768);
    attn_fwd<<<NBATCH * NHEAD * (T_SEQ / 64), 256, 0, stream>>>(qkv, yb);
    gemm_bt<0><<<dim3(6, 64), 256, 0, stream>>>(yb, Wpt, b_proj, d_out, 8192, 768, 768);
}

// Round 2
// 194.708 us; speedup vs baseline: 1.1584x; 1.1584x over previous
//
#include <hip/hip_runtime.h>
#include <hip/hip_bf16.h>

// Problem constants (fixed shapes)
#define T_SEQ 1024
#define NBATCH 8
#define NHEAD 12
#define HD 64
#define CDIM 768
#define C3 2304
#define ATT_SCALE 0.125f   // 1/sqrt(64)

typedef __attribute__((ext_vector_type(8))) __bf16 bf16x8;
typedef __attribute__((ext_vector_type(4))) __bf16 bf16x4;
typedef __attribute__((ext_vector_type(2))) __bf16 bf16x2;
typedef __attribute__((ext_vector_type(4))) float  f32x4;

__device__ __forceinline__ f32x4 mfma_bf16(bf16x8 a, bf16x8 b, f32x4 c) {
    return __builtin_amdgcn_mfma_f32_16x16x32_bf16(a, b, c, 0, 0, 0);
}

// async global->LDS, 16B per lane; LDS dest must be wave-uniform base (+lane*16 implicit)
__device__ __forceinline__ void gload16(const void* g, void* l) {
    __builtin_amdgcn_global_load_lds(
        (const __attribute__((address_space(1))) unsigned int*)g,
        (__attribute__((address_space(3))) unsigned int*)l, 16, 0, 0);
}

// ---------------- f32 -> bf16 convert (vectorized) ----------------
__global__ __launch_bounds__(256) void cvt_f32_bf16(const float* __restrict__ in,
                                                    __bf16* __restrict__ out, int n4) {
    int i = blockIdx.x * 256 + threadIdx.x;
    if (i < n4) {
        float4 v = ((const float4*)in)[i];
        bf16x4 o = { (__bf16)v.x, (__bf16)v.y, (__bf16)v.z, (__bf16)v.w };
        ((bf16x4*)out)[i] = o;
    }
}

// ---------------- transpose + convert: W [R][C] f32 -> Wt [C][R] bf16 ----------------
__global__ __launch_bounds__(256) void transpose_cvt(const float* __restrict__ W,
                                                     __bf16* __restrict__ Wt,
                                                     int R, int C) {
    __shared__ float tile[32][33];
    const int c0 = blockIdx.x * 32, r0 = blockIdx.y * 32;
    const int tc = threadIdx.x & 31, tr = threadIdx.x >> 5;   // tr in 0..7
#pragma unroll
    for (int i = 0; i < 4; ++i)
        tile[tr + i * 8][tc] = W[(size_t)(r0 + tr + i * 8) * C + c0 + tc];
    __syncthreads();
#pragma unroll
    for (int i = 0; i < 4; ++i)
        Wt[(size_t)(c0 + tr + i * 8) * R + r0 + tc] = (__bf16)tile[tc][tr + i * 8];
}

// ---------------- GEMM: C[M][N] = A[M][K] @ Bt[N][K]^T + bias ----------------
template<int OUT_BF16>
__global__ __launch_bounds__(256) void gemm_bt(const __bf16* __restrict__ A,
                                               const __bf16* __restrict__ Bt,
                                               const float* __restrict__ bias,
                                               void* __restrict__ Cout,
                                               int M, int N, int K) {
    __shared__ __align__(16) __bf16 sA[128 * 32];
    __shared__ __align__(16) __bf16 sB[128 * 32];
    const int t = threadIdx.x, l = t & 63, w = t >> 6;
    const int lr = l & 15, lk = l >> 4;
    const int wr = w >> 1, wc = w & 1;
    const int m0 = blockIdx.y * 128, n0 = blockIdx.x * 128;

    f32x4 acc[4][4];
#pragma unroll
    for (int m = 0; m < 4; ++m)
#pragma unroll
        for (int n = 0; n < 4; ++n) acc[m][n] = f32x4{0.f, 0.f, 0.f, 0.f};

    for (int k0 = 0; k0 < K; k0 += 32) {
#pragma unroll
        for (int i = 0; i < 2; ++i) {
            int idx = i * 256 + t;
            int r = idx >> 2, c = (idx & 3) << 3;
            gload16(A + (size_t)(m0 + r) * K + k0 + c, (char*)sA + (i * 256 + w * 64) * 16);
            gload16(Bt + (size_t)(n0 + r) * K + k0 + c, (char*)sB + (i * 256 + w * 64) * 16);
        }
        __syncthreads();

        bf16x8 af[4], bg[4];
#pragma unroll
        for (int m = 0; m < 4; ++m)
            af[m] = *(const bf16x8*)(sA + (wr * 64 + m * 16 + lr) * 32 + lk * 8);
#pragma unroll
        for (int n = 0; n < 4; ++n)
            bg[n] = *(const bf16x8*)(sB + (wc * 64 + n * 16 + lr) * 32 + lk * 8);
#pragma unroll
        for (int m = 0; m < 4; ++m)
#pragma unroll
            for (int n = 0; n < 4; ++n)
                acc[m][n] = mfma_bf16(af[m], bg[n], acc[m][n]);
        __syncthreads();
    }

#pragma unroll
    for (int n = 0; n < 4; ++n) {
        int col = n0 + wc * 64 + n * 16 + lr;
        float bv = bias[col];
#pragma unroll
        for (int m = 0; m < 4; ++m) {
            int row0 = m0 + wr * 64 + m * 16 + lk * 4;
#pragma unroll
            for (int j = 0; j < 4; ++j) {
                float v = acc[m][n][j] + bv;
                if (OUT_BF16)
                    ((__bf16*)Cout)[(size_t)(row0 + j) * N + col] = (__bf16)v;
                else
                    ((float*)Cout)[(size_t)(row0 + j) * N + col] = v;
            }
        }
    }
}

// ---------------- causal flash attention (swapped-QK^T, dbuf V, 1 barrier/tile) ----
// 768 blocks; block = (pair pr, h, b) handles q-tiles {pr, 15-pr} (uniform 17 tiles).
// 4 waves x 16 q-rows. S^T = K·Q^T so each lane owns ONE q-row -> 2-shuffle reductions.
__global__ __launch_bounds__(256, 3) void attn_fwd(const __bf16* __restrict__ qkv,
                                                   __bf16* __restrict__ y) {
    const int tid = threadIdx.x, l = tid & 63, w = tid >> 6;
    const int lr = l & 15, lk = l >> 4;
    const int bid = blockIdx.x;
    // XCD swizzle: all 8 pair-blocks of one (b,h) share bid%8 -> same XCD L2
    const int pr = bid / 96;                 // 0..7
    const int hb = bid % 96;
    const int h = hb % NHEAD;
    const int b = hb / NHEAD;

    __shared__ __align__(16) __bf16 sV[2][64][64];   // XOR-swizzled columns
    __shared__ __align__(16) __bf16 sP[4][16][72];   // per-wave P tile [q][key]

    const size_t baseQ = (size_t)b * T_SEQ * C3 + h * HD;
    const __bf16* Kp = qkv + baseQ + CDIM;
    const __bf16* Vp = qkv + baseQ + 2 * CDIM;

    // V staging geometry: idx=i*256+tid -> key=i*32+(tid>>3), d-block=(tid&7)*8
    const int vk0 = tid >> 3;          // + i*32
    const int vc = (tid & 7) << 3;
    const int vg = vc >> 3;            // row-group for swizzle

#pragma unroll 1
    for (int job = 0; job < 2; ++job) {
        const int qt = (job == 0) ? pr : 15 - pr;
        const int q0 = qt * 64;
        const int nt = qt + 1;
        const int q_abs = q0 + w * 16 + lr;

        // Q fragments
        const size_t rowQ = baseQ + (size_t)(q0 + w * 16 + lr) * C3;
        bf16x8 qa0 = *(const bf16x8*)(qkv + rowQ + lk * 8);
        bf16x8 qa1 = *(const bf16x8*)(qkv + rowQ + 32 + lk * 8);

        f32x4 acc[4];
#pragma unroll
        for (int fd = 0; fd < 4; ++fd) acc[fd] = f32x4{0.f, 0.f, 0.f, 0.f};
        float mrun = -1e30f, lrun = 0.f;

        bf16x8 kA[8], kB[8], vreg[2];
        // prologue: K(0)->kA, V(0)->vreg
#pragma unroll
        for (int fc = 0; fc < 4; ++fc) {
            const __bf16* p = Kp + (size_t)(fc * 16 + lr) * C3 + lk * 8;
            kA[fc * 2 + 0] = *(const bf16x8*)p;
            kA[fc * 2 + 1] = *(const bf16x8*)(p + 32);
        }
#pragma unroll
        for (int i = 0; i < 2; ++i)
            vreg[i] = *(const bf16x8*)(Vp + (size_t)(i * 32 + vk0) * C3 + vc);
        __syncthreads();   // prev job's PV reads done before overwriting sV[0]
#pragma unroll
        for (int i = 0; i < 2; ++i) {
            int key = i * 32 + vk0;
#pragma unroll
            for (int e = 0; e < 8; ++e)
                sV[0][vc + e][key ^ ((e ^ vg) << 3)] = vreg[i][e];
        }

        auto tile = [&](int t, bf16x8(&kcur)[8], bf16x8(&knxt)[8]) {
            const int kv0 = t * 64;
            const int cur = t & 1;
            const bool pre = (t + 1 < nt);
            const int kvp = pre ? kv0 + 64 : kv0;
            // issue prefetches (V then K) — land after PV, under compute
            if (pre) {
#pragma unroll
                for (int i = 0; i < 2; ++i)
                    vreg[i] = *(const bf16x8*)(Vp + (size_t)(kvp + i * 32 + vk0) * C3 + vc);
#pragma unroll
                for (int fc = 0; fc < 4; ++fc) {
                    const __bf16* p = Kp + (size_t)(kvp + fc * 16 + lr) * C3 + lk * 8;
                    knxt[fc * 2 + 0] = *(const bf16x8*)p;
                    knxt[fc * 2 + 1] = *(const bf16x8*)(p + 32);
                }
            }
            // S^T = K·Q^T : lane (lr,lk) holds S[q=q0+w*16+lr][key=kv0+fc*16+lk*4+j]
            f32x4 s[4];
#pragma unroll
            for (int fc = 0; fc < 4; ++fc) {
                f32x4 z = f32x4{0.f, 0.f, 0.f, 0.f};
                z = mfma_bf16(kcur[fc * 2 + 0], qa0, z);
                z = mfma_bf16(kcur[fc * 2 + 1], qa1, z);
                s[fc] = z;
            }
            // online softmax — per-lane scalar m/l, 2-shuffle reductions
            float ps[4][4];
#pragma unroll
            for (int fc = 0; fc < 4; ++fc)
#pragma unroll
                for (int j = 0; j < 4; ++j) {
                    int key = kv0 + fc * 16 + lk * 4 + j;
                    ps[fc][j] = (key <= q_abs) ? s[fc][j] * ATT_SCALE : -1e30f;
                }
            float mt = -1e30f;
#pragma unroll
            for (int fc = 0; fc < 4; ++fc)
#pragma unroll
                for (int j = 0; j < 4; ++j) mt = fmaxf(mt, ps[fc][j]);
            mt = fmaxf(mt, __shfl_xor(mt, 16, 64));
            mt = fmaxf(mt, __shfl_xor(mt, 32, 64));
            const float mn = fmaxf(mrun, mt);
            const float corr = __expf(mrun - mn);
            mrun = mn;
            float rs = 0.f;
#pragma unroll
            for (int fc = 0; fc < 4; ++fc)
#pragma unroll
                for (int j = 0; j < 4; ++j) {
                    float p = __expf(ps[fc][j] - mn);
                    ps[fc][j] = p;
                    rs += p;
                }
            rs += __shfl_xor(rs, 16, 64);
            rs += __shfl_xor(rs, 32, 64);
            lrun = lrun * corr + rs;
            float cj[4];
#pragma unroll
            for (int j = 0; j < 4; ++j) cj[j] = __shfl(corr, lk * 4 + j, 64);
#pragma unroll
            for (int fd = 0; fd < 4; ++fd)
#pragma unroll
                for (int j = 0; j < 4; ++j) acc[fd][j] *= cj[j];
            // P -> sP (paired b32 writes)
#pragma unroll
            for (int fc = 0; fc < 4; ++fc)
#pragma unroll
                for (int jp = 0; jp < 2; ++jp) {
                    bf16x2 pk = { (__bf16)ps[fc][jp * 2], (__bf16)ps[fc][jp * 2 + 1] };
                    *(bf16x2*)&sP[w][lr][fc * 16 + lk * 4 + jp * 2] = pk;
                }
            __syncthreads();   // sV[cur] writes (prev iter) + own sP visible
            // O += P·V from sV[cur] (swizzled b128 reads)
#pragma unroll
            for (int ks = 0; ks < 2; ++ks) {
                bf16x8 pa = *(const bf16x8*)&sP[w][lr][ks * 32 + lk * 8];
#pragma unroll
                for (int fd = 0; fd < 4; ++fd) {
                    int d = fd * 16 + lr;
                    int sw = ((d & 7) ^ ((d >> 3) & 7)) << 3;
                    bf16x8 vb = *(const bf16x8*)&sV[cur][d][(ks * 32 + lk * 8) ^ sw];
                    acc[fd] = mfma_bf16(pa, vb, acc[fd]);
                }
            }
            // stage V(t+1) -> sV[cur^1] (vmcnt hidden under QK^T+softmax+PV)
            if (pre) {
#pragma unroll
                for (int i = 0; i < 2; ++i) {
                    int key = i * 32 + vk0;
#pragma unroll
                    for (int e = 0; e < 8; ++e)
                        sV[cur ^ 1][vc + e][key ^ ((e ^ vg) << 3)] = vreg[i][e];
                }
            }
        };

        for (int t = 0; t < nt; t += 2) {
            tile(t, kA, kB);
            if (t + 1 < nt) tile(t + 1, kB, kA);
        }

        // epilogue: y[b*T+q][h*64+d], q = q0+w*16+lk*4+j, d = fd*16+lr
        float linv[4];
#pragma unroll
        for (int j = 0; j < 4; ++j) linv[j] = 1.f / __shfl(lrun, lk * 4 + j, 64);
        const size_t yrow0 = (size_t)(b * T_SEQ + q0 + w * 16 + lk * 4);
#pragma unroll
        for (int fd = 0; fd < 4; ++fd) {
            int col = h * HD + fd * 16 + lr;
#pragma unroll
            for (int j = 0; j < 4; ++j)
                y[(yrow0 + j) * CDIM + col] = (__bf16)(acc[fd][j] * linv[j]);
        }
    }
}

// ---------------- launch ----------------
extern "C" void kernel_launch(void* const* d_in, const int* in_sizes, int n_in,
                              void* d_out, int out_size, void* d_ws, size_t ws_size,
                              hipStream_t stream) {
    const float* x      = (const float*)d_in[0];
    const float* W_attn = (const float*)d_in[1];
    const float* b_attn = (const float*)d_in[2];
    const float* W_proj = (const float*)d_in[3];
    const float* b_proj = (const float*)d_in[4];

    __bf16* xb  = (__bf16*)d_ws;                       // [8192][768]
    __bf16* Wat = xb  + (size_t)8192 * 768;            // [2304][768]  (W_attn^T)
    __bf16* Wpt = Wat + (size_t)2304 * 768;            // [768][768]   (W_proj^T)
    __bf16* qkv = Wpt + (size_t)768 * 768;             // [8192][2304]
    __bf16* yb  = qkv + (size_t)8192 * 2304;           // [8192][768]

    cvt_f32_bf16<<<6144, 256, 0, stream>>>(x, xb, (8192 * 768) / 4);
    transpose_cvt<<<dim3(72, 24), 256, 0, stream>>>(W_attn, Wat, 768, 2304);
    transpose_cvt<<<dim3(24, 24), 256, 0, stream>>>(W_proj, Wpt, 768, 768);

    gemm_bt<1><<<dim3(18, 64), 256, 0, stream>>>(xb, Wat, b_attn, (void*)qkv, 8192, 2304, 768);
    attn_fwd<<<NBATCH * NHEAD * 8, 256, 0, stream>>>(qkv, yb);
    gemm_bt<0><<<dim3(6, 64), 256, 0, stream>>>(yb, Wpt, b_proj, d_out, 8192, 768, 768);
}

// Round 3
// 140.923 us; speedup vs baseline: 1.6006x; 1.3817x over previous
//
#include <hip/hip_runtime.h>
#include <hip/hip_bf16.h>

// Problem constants (fixed shapes)
#define T_SEQ 1024
#define NBATCH 8
#define NHEAD 12
#define HD 64
#define CDIM 768
#define C3 2304
#define ATT_SCALE 0.125f   // 1/sqrt(64)

typedef __attribute__((ext_vector_type(8))) __bf16 bf16x8;
typedef __attribute__((ext_vector_type(4))) __bf16 bf16x4;
typedef __attribute__((ext_vector_type(2))) __bf16 bf16x2;
typedef __attribute__((ext_vector_type(4))) float  f32x4;

__device__ __forceinline__ f32x4 mfma_bf16(bf16x8 a, bf16x8 b, f32x4 c) {
    return __builtin_amdgcn_mfma_f32_16x16x32_bf16(a, b, c, 0, 0, 0);
}

// async global->LDS, 16B per lane; LDS dest is wave-uniform base (+lane*16 implicit)
__device__ __forceinline__ void gload16(const void* g, void* l) {
    __builtin_amdgcn_global_load_lds(
        (const __attribute__((address_space(1))) unsigned int*)g,
        (__attribute__((address_space(3))) unsigned int*)l, 16, 0, 0);
}

// ---------------- f32 -> bf16 convert (vectorized) ----------------
__global__ __launch_bounds__(256) void cvt_f32_bf16(const float* __restrict__ in,
                                                    __bf16* __restrict__ out, int n4) {
    int i = blockIdx.x * 256 + threadIdx.x;
    if (i < n4) {
        float4 v = ((const float4*)in)[i];
        bf16x4 o = { (__bf16)v.x, (__bf16)v.y, (__bf16)v.z, (__bf16)v.w };
        ((bf16x4*)out)[i] = o;
    }
}

// ---------------- transpose + convert: W [R][C] f32 -> Wt [C][R] bf16 ----------------
__global__ __launch_bounds__(256) void transpose_cvt(const float* __restrict__ W,
                                                     __bf16* __restrict__ Wt,
                                                     int R, int C) {
    __shared__ float tile[32][33];
    const int c0 = blockIdx.x * 32, r0 = blockIdx.y * 32;
    const int tc = threadIdx.x & 31, tr = threadIdx.x >> 5;   // tr in 0..7
#pragma unroll
    for (int i = 0; i < 4; ++i)
        tile[tr + i * 8][tc] = W[(size_t)(r0 + tr + i * 8) * C + c0 + tc];
    __syncthreads();
#pragma unroll
    for (int i = 0; i < 4; ++i)
        Wt[(size_t)(c0 + tr + i * 8) * R + r0 + tc] = (__bf16)tile[tc][tr + i * 8];
}

// ---------------- GEMM: C[M][N] = A[M][K] @ Bt[N][K]^T + bias ----------------
// 128x128 tile, BK=32, 4 waves; 1D grid with XCD-aware swizzle (nwg % 8 == 0).
template<int OUT_BF16>
__global__ __launch_bounds__(256) void gemm_bt(const __bf16* __restrict__ A,
                                               const __bf16* __restrict__ Bt,
                                               const float* __restrict__ bias,
                                               void* __restrict__ Cout,
                                               int M, int N, int K, int nbx) {
    __shared__ __align__(16) __bf16 sA[128 * 32];
    __shared__ __align__(16) __bf16 sB[128 * 32];
    const int t = threadIdx.x, l = t & 63, w = t >> 6;
    const int lr = l & 15, lk = l >> 4;
    const int wr = w >> 1, wc = w & 1;
    // XCD swizzle: consecutive swz ids (same XCD) share the A row-panel
    const int q = gridDim.x >> 3;
    const int swz = (blockIdx.x & 7) * q + (blockIdx.x >> 3);
    const int m0 = (swz / nbx) * 128, n0 = (swz % nbx) * 128;

    f32x4 acc[4][4];
#pragma unroll
    for (int m = 0; m < 4; ++m)
#pragma unroll
        for (int n = 0; n < 4; ++n) acc[m][n] = f32x4{0.f, 0.f, 0.f, 0.f};

    for (int k0 = 0; k0 < K; k0 += 32) {
#pragma unroll
        for (int i = 0; i < 2; ++i) {
            int idx = i * 256 + t;
            int r = idx >> 2, c = (idx & 3) << 3;
            gload16(A + (size_t)(m0 + r) * K + k0 + c, (char*)sA + (i * 256 + w * 64) * 16);
            gload16(Bt + (size_t)(n0 + r) * K + k0 + c, (char*)sB + (i * 256 + w * 64) * 16);
        }
        __syncthreads();

        bf16x8 af[4], bg[4];
#pragma unroll
        for (int m = 0; m < 4; ++m)
            af[m] = *(const bf16x8*)(sA + (wr * 64 + m * 16 + lr) * 32 + lk * 8);
#pragma unroll
        for (int n = 0; n < 4; ++n)
            bg[n] = *(const bf16x8*)(sB + (wc * 64 + n * 16 + lr) * 32 + lk * 8);
#pragma unroll
        for (int m = 0; m < 4; ++m)
#pragma unroll
            for (int n = 0; n < 4; ++n)
                acc[m][n] = mfma_bf16(af[m], bg[n], acc[m][n]);
        __syncthreads();
    }

#pragma unroll
    for (int n = 0; n < 4; ++n) {
        int col = n0 + wc * 64 + n * 16 + lr;
        float bv = bias[col];
#pragma unroll
        for (int m = 0; m < 4; ++m) {
            int row0 = m0 + wr * 64 + m * 16 + lk * 4;
#pragma unroll
            for (int j = 0; j < 4; ++j) {
                float v = acc[m][n][j] + bv;
                if (OUT_BF16)
                    ((__bf16*)Cout)[(size_t)(row0 + j) * N + col] = (__bf16)v;
                else
                    ((float*)Cout)[(size_t)(row0 + j) * N + col] = v;
            }
        }
    }
}

// ---------------- causal flash attention ----------------
// 768 blocks; block = (pair pr, h, b) handles q-tiles {pr, 15-pr} (uniform 17 tiles).
// 4 waves x 16 q-rows; swapped QK^T (lane owns one q-row -> 2-shuffle softmax).
// K: dbuf LDS via global_load_lds with source-pre-swizzled chunks (linear dest).
// V: dbuf LDS, reg-staged transpose with XOR swizzle. 1 barrier per KV tile.
__global__ __launch_bounds__(256, 2) void attn_fwd(const __bf16* __restrict__ qkv,
                                                   __bf16* __restrict__ y) {
    const int tid = threadIdx.x, l = tid & 63, w = tid >> 6;
    const int lr = l & 15, lk = l >> 4;
    const int r7 = lr & 7;
    const int bid = blockIdx.x;
    // XCD swizzle: all 8 pair-blocks of one (b,h) share bid%8 -> same XCD L2
    const int pr = bid / 96;                 // 0..7
    const int hb = bid % 96;
    const int h = hb % NHEAD;
    const int b = hb / NHEAD;

    __shared__ __align__(16) __bf16 sK[2][64][64];   // chunk-swizzled: phys c = log c ^ (row&7)
    __shared__ __align__(16) __bf16 sV[2][64][64];   // [d][key], XOR-swizzled columns
    __shared__ __align__(16) __bf16 sP[4][16][72];   // per-wave P tile [q][key] (no barrier)

    const size_t baseQ = (size_t)b * T_SEQ * C3 + h * HD;
    const __bf16* Kp = qkv + baseQ + CDIM;
    const __bf16* Vp = qkv + baseQ + 2 * CDIM;

    // V staging geometry: key = i*32 + (tid>>3), d-block = (tid&7)*8
    const int vk0 = tid >> 3;
    const int vc = (tid & 7) << 3;
    const int vg = tid & 7;
    // K staging geometry (gload16): phys slot row = i*32 + (tid>>3), chunk c = tid&7;
    // fetch global chunk c ^ (row&7) so linear DMA lands swizzled.
    const int krow = tid >> 3;               // + i*32 (i*32 % 8 == 0)
    const int kchunk = (tid & 7) ^ ((tid >> 3) & 7);

#pragma unroll 1
    for (int job = 0; job < 2; ++job) {
        const int qt = (job == 0) ? pr : 15 - pr;
        const int q0 = qt * 64;
        const int nt = qt + 1;
        const int q_abs = q0 + w * 16 + lr;

        // Q fragments (regs, whole job)
        const size_t rowQ = baseQ + (size_t)(q0 + w * 16 + lr) * C3;
        bf16x8 qa0 = *(const bf16x8*)(qkv + rowQ + lk * 8);
        bf16x8 qa1 = *(const bf16x8*)(qkv + rowQ + 32 + lk * 8);

        f32x4 acc[4];
#pragma unroll
        for (int fd = 0; fd < 4; ++fd) acc[fd] = f32x4{0.f, 0.f, 0.f, 0.f};
        float mrun = -1e30f, lrun = 0.f;

        bf16x8 vreg[2];
        // ---- prologue: stage K(0), V(0) into buffer 0 ----
#pragma unroll
        for (int i = 0; i < 2; ++i)
            vreg[i] = *(const bf16x8*)(Vp + (size_t)(i * 32 + vk0) * C3 + vc);
#pragma unroll
        for (int i = 0; i < 2; ++i)
            gload16(Kp + (size_t)(i * 32 + krow) * C3 + kchunk * 8,
                    (char*)&sK[0][0][0] + (i * 256 + w * 64) * 16);
#pragma unroll
        for (int i = 0; i < 2; ++i) {
            int key = i * 32 + vk0;
#pragma unroll
            for (int e = 0; e < 8; ++e)
                sV[0][vc + e][key ^ ((e ^ vg) << 3)] = vreg[i][e];
        }
        __syncthreads();   // K DMA + V writes visible (also fences prev job's reads)

#pragma unroll 1
        for (int t = 0; t < nt; ++t) {
            const int kv0 = t * 64;
            const int cur = t & 1, nxt = cur ^ 1;
            const bool pre = (t + 1 < nt);
            // ---- issue next-tile loads first (latency hides under compute) ----
            if (pre) {
                const int kvp = kv0 + 64;
#pragma unroll
                for (int i = 0; i < 2; ++i)
                    vreg[i] = *(const bf16x8*)(Vp + (size_t)(kvp + i * 32 + vk0) * C3 + vc);
#pragma unroll
                for (int i = 0; i < 2; ++i)
                    gload16(Kp + (size_t)(kvp + i * 32 + krow) * C3 + kchunk * 8,
                            (char*)&sK[nxt][0][0] + (i * 256 + w * 64) * 16);
            }
            // ---- S^T = K·Q^T : lane (lr,lk) -> S[q=q0+w*16+lr][key=kv0+fc*16+lk*4+j]
            f32x4 s[4];
#pragma unroll
            for (int fc = 0; fc < 4; ++fc) {
                const __bf16* kr = &sK[cur][fc * 16 + lr][0];
                bf16x8 k0 = *(const bf16x8*)(kr + ((lk ^ r7) << 3));
                bf16x8 k1 = *(const bf16x8*)(kr + (((4 + lk) ^ r7) << 3));
                f32x4 z = f32x4{0.f, 0.f, 0.f, 0.f};
                z = mfma_bf16(k0, qa0, z);
                z = mfma_bf16(k1, qa1, z);
                s[fc] = z;
            }
            // ---- online softmax: per-lane m/l, 2-shuffle reductions ----
            float ps[4][4];
#pragma unroll
            for (int fc = 0; fc < 4; ++fc)
#pragma unroll
                for (int j = 0; j < 4; ++j) {
                    int key = kv0 + fc * 16 + lk * 4 + j;
                    ps[fc][j] = (key <= q_abs) ? s[fc][j] * ATT_SCALE : -1e30f;
                }
            float mt = -1e30f;
#pragma unroll
            for (int fc = 0; fc < 4; ++fc)
#pragma unroll
                for (int j = 0; j < 4; ++j) mt = fmaxf(mt, ps[fc][j]);
            mt = fmaxf(mt, __shfl_xor(mt, 16, 64));
            mt = fmaxf(mt, __shfl_xor(mt, 32, 64));
            const float mn = fmaxf(mrun, mt);
            const float corr = __expf(mrun - mn);
            mrun = mn;
            float rs = 0.f;
#pragma unroll
            for (int fc = 0; fc < 4; ++fc)
#pragma unroll
                for (int j = 0; j < 4; ++j) {
                    float p = __expf(ps[fc][j] - mn);
                    ps[fc][j] = p;
                    rs += p;
                }
            rs += __shfl_xor(rs, 16, 64);
            rs += __shfl_xor(rs, 32, 64);
            lrun = lrun * corr + rs;
            float cj[4];
#pragma unroll
            for (int j = 0; j < 4; ++j) cj[j] = __shfl(corr, lk * 4 + j, 64);
#pragma unroll
            for (int fd = 0; fd < 4; ++fd)
#pragma unroll
                for (int j = 0; j < 4; ++j) acc[fd][j] *= cj[j];
            // ---- P -> sP (per-wave private; paired b32 writes) ----
#pragma unroll
            for (int fc = 0; fc < 4; ++fc)
#pragma unroll
                for (int jp = 0; jp < 2; ++jp) {
                    bf16x2 pk = { (__bf16)ps[fc][jp * 2], (__bf16)ps[fc][jp * 2 + 1] };
                    *(bf16x2*)&sP[w][lr][fc * 16 + lk * 4 + jp * 2] = pk;
                }
            // ---- O += P·V from sV[cur] (swizzled b128 reads) ----
#pragma unroll
            for (int ks = 0; ks < 2; ++ks) {
                bf16x8 pa = *(const bf16x8*)&sP[w][lr][ks * 32 + lk * 8];
#pragma unroll
                for (int fd = 0; fd < 4; ++fd) {
                    int d = fd * 16 + lr;
                    int sw = ((d & 7) ^ ((d >> 3) & 7)) << 3;
                    bf16x8 vb = *(const bf16x8*)&sV[cur][d][(ks * 32 + lk * 8) ^ sw];
                    acc[fd] = mfma_bf16(pa, vb, acc[fd]);
                }
            }
            // ---- stage V(t+1) into sV[nxt] ----
            if (pre) {
#pragma unroll
                for (int i = 0; i < 2; ++i) {
                    int key = i * 32 + vk0;
#pragma unroll
                    for (int e = 0; e < 8; ++e)
                        sV[nxt][vc + e][key ^ ((e ^ vg) << 3)] = vreg[i][e];
                }
            }
            __syncthreads();   // drains K DMA (vmcnt) + V writes for tile t+1
        }

        // ---- epilogue: y[b*T+q][h*64+d], q = q0+w*16+lk*4+j, d = fd*16+lr ----
        float linv[4];
#pragma unroll
        for (int j = 0; j < 4; ++j) linv[j] = 1.f / __shfl(lrun, lk * 4 + j, 64);
        const size_t yrow0 = (size_t)(b * T_SEQ + q0 + w * 16 + lk * 4);
#pragma unroll
        for (int fd = 0; fd < 4; ++fd) {
            int col = h * HD + fd * 16 + lr;
#pragma unroll
            for (int j = 0; j < 4; ++j)
                y[(yrow0 + j) * CDIM + col] = (__bf16)(acc[fd][j] * linv[j]);
        }
    }
}

// ---------------- launch ----------------
extern "C" void kernel_launch(void* const* d_in, const int* in_sizes, int n_in,
                              void* d_out, int out_size, void* d_ws, size_t ws_size,
                              hipStream_t stream) {
    const float* x      = (const float*)d_in[0];
    const float* W_attn = (const float*)d_in[1];
    const float* b_attn = (const float*)d_in[2];
    const float* W_proj = (const float*)d_in[3];
    const float* b_proj = (const float*)d_in[4];

    __bf16* xb  = (__bf16*)d_ws;                       // [8192][768]
    __bf16* Wat = xb  + (size_t)8192 * 768;            // [2304][768]  (W_attn^T)
    __bf16* Wpt = Wat + (size_t)2304 * 768;            // [768][768]   (W_proj^T)
    __bf16* qkv = Wpt + (size_t)768 * 768;             // [8192][2304]
    __bf16* yb  = qkv + (size_t)8192 * 2304;           // [8192][768]

    cvt_f32_bf16<<<6144, 256, 0, stream>>>(x, xb, (8192 * 768) / 4);
    transpose_cvt<<<dim3(72, 24), 256, 0, stream>>>(W_attn, Wat, 768, 2304);
    transpose_cvt<<<dim3(24, 24), 256, 0, stream>>>(W_proj, Wpt, 768, 768);

    gemm_bt<1><<<18 * 64, 256, 0, stream>>>(xb, Wat, b_attn, (void*)qkv, 8192, 2304, 768, 18);
    attn_fwd<<<NBATCH * NHEAD * 8, 256, 0, stream>>>(qkv, yb);
    gemm_bt<0><<<6 * 64, 256, 0, stream>>>(yb, Wpt, b_proj, d_out, 8192, 768, 768, 6);
}

// Round 4
// 123.448 us; speedup vs baseline: 1.8271x; 1.1416x over previous
//
#include <hip/hip_runtime.h>
#include <hip/hip_bf16.h>

// Problem constants (fixed shapes)
#define T_SEQ 1024
#define NBATCH 8
#define NHEAD 12
#define HD 64
#define CDIM 768
#define C3 2304
#define ATT_SCALE 0.125f   // 1/sqrt(64)

typedef __attribute__((ext_vector_type(8))) __bf16 bf16x8;
typedef __attribute__((ext_vector_type(4))) __bf16 bf16x4;
typedef __attribute__((ext_vector_type(2))) __bf16 bf16x2;
typedef __attribute__((ext_vector_type(4))) float  f32x4;

__device__ __forceinline__ f32x4 mfma_bf16(bf16x8 a, bf16x8 b, f32x4 c) {
    return __builtin_amdgcn_mfma_f32_16x16x32_bf16(a, b, c, 0, 0, 0);
}

// async global->LDS, 16B per lane; LDS dest is wave-uniform base (+lane*16 implicit)
__device__ __forceinline__ void gload16(const void* g, void* l) {
    __builtin_amdgcn_global_load_lds(
        (const __attribute__((address_space(1))) unsigned int*)g,
        (__attribute__((address_space(3))) unsigned int*)l, 16, 0, 0);
}

// ---------------- f32 -> bf16 convert (vectorized) ----------------
__global__ __launch_bounds__(256) void cvt_f32_bf16(const float* __restrict__ in,
                                                    __bf16* __restrict__ out, int n4) {
    int i = blockIdx.x * 256 + threadIdx.x;
    if (i < n4) {
        float4 v = ((const float4*)in)[i];
        bf16x4 o = { (__bf16)v.x, (__bf16)v.y, (__bf16)v.z, (__bf16)v.w };
        ((bf16x4*)out)[i] = o;
    }
}

// ---------------- transpose + convert: W [R][C] f32 -> Wt [C][R] bf16 ----------------
__global__ __launch_bounds__(256) void transpose_cvt(const float* __restrict__ W,
                                                     __bf16* __restrict__ Wt,
                                                     int R, int C) {
    __shared__ float tile[32][33];
    const int c0 = blockIdx.x * 32, r0 = blockIdx.y * 32;
    const int tc = threadIdx.x & 31, tr = threadIdx.x >> 5;   // tr in 0..7
#pragma unroll
    for (int i = 0; i < 4; ++i)
        tile[tr + i * 8][tc] = W[(size_t)(r0 + tr + i * 8) * C + c0 + tc];
    __syncthreads();
#pragma unroll
    for (int i = 0; i < 4; ++i)
        Wt[(size_t)(c0 + tr + i * 8) * R + r0 + tc] = (__bf16)tile[tc][tr + i * 8];
}

// ---------------- GEMM: C[M][N] = A[M][K] @ Bt[N][K]^T + bias ----------------
// 128x128 tile, BK=32, 4 waves; 2-phase double-buffered LDS (1 barrier/K-step,
// stage(t+1) issued before compute(t)); both-sides XOR chunk-swizzle so the
// stride-64B ds_read_b128 is 2-way (free). 1D grid, XCD-aware swizzle (nwg%8==0).
template<int OUT_BF16>
__global__ __launch_bounds__(256) void gemm_bt(const __bf16* __restrict__ A,
                                               const __bf16* __restrict__ Bt,
                                               const float* __restrict__ bias,
                                               void* __restrict__ Cout,
                                               int M, int N, int K, int nbx) {
    __shared__ __align__(16) __bf16 sA[2][128 * 32];
    __shared__ __align__(16) __bf16 sB[2][128 * 32];
    const int t = threadIdx.x, l = t & 63, w = t >> 6;
    const int lr = l & 15, lk = l >> 4;
    const int wr = w >> 1, wc = w & 1;
    // XCD swizzle: consecutive swz ids (same XCD) share the A row-panel
    const int q = gridDim.x >> 3;
    const int swz = (blockIdx.x & 7) * q + (blockIdx.x >> 3);
    const int m0 = (swz / nbx) * 128, n0 = (swz % nbx) * 128;

    // staging geometry: idx = i*256+t -> row r=idx>>2, chunk c=idx&3 (16B chunks);
    // fetch global chunk c ^ s(r), s(r)=(r&3)^((r>>2)&3)  [both-sides swizzle]
    const int r_st = t >> 2;                       // + i*64
    const int c_st = t & 3;
    // i*64 doesn't change s(r) bits? (i*64)&3=0, ((i*64)>>2)&3 = (i*16)&3 = 0 -> ok
    const int sw_st = (r_st & 3) ^ ((r_st >> 2) & 3);
    const int g_off = (c_st ^ sw_st) << 3;         // element offset within row
    // read-side swizzle: row R = wr*64+m*16+lr -> s(R) = (lr&3)^((lr>>2)&3)
    const int sw_rd = (lr & 3) ^ ((lr >> 2) & 3);

    f32x4 acc[4][4];
#pragma unroll
    for (int m = 0; m < 4; ++m)
#pragma unroll
        for (int n = 0; n < 4; ++n) acc[m][n] = f32x4{0.f, 0.f, 0.f, 0.f};

    const int nk = K >> 5;
    // prologue: stage tile 0 into buffer 0
#pragma unroll
    for (int i = 0; i < 2; ++i) {
        int r = i * 64 + r_st;
        gload16(A + (size_t)(m0 + r) * K + g_off, (char*)&sA[0][0] + (i * 256 + w * 64) * 16);
        gload16(Bt + (size_t)(n0 + r) * K + g_off, (char*)&sB[0][0] + (i * 256 + w * 64) * 16);
    }
    __syncthreads();

    for (int kt = 0; kt < nk; ++kt) {
        const int cur = kt & 1;
        // issue next tile's staging first — flies under the MFMAs below
        if (kt + 1 < nk) {
            const int k0 = (kt + 1) << 5;
#pragma unroll
            for (int i = 0; i < 2; ++i) {
                int r = i * 64 + r_st;
                gload16(A + (size_t)(m0 + r) * K + k0 + g_off,
                        (char*)&sA[cur ^ 1][0] + (i * 256 + w * 64) * 16);
                gload16(Bt + (size_t)(n0 + r) * K + k0 + g_off,
                        (char*)&sB[cur ^ 1][0] + (i * 256 + w * 64) * 16);
            }
        }
        bf16x8 af[4], bg[4];
#pragma unroll
        for (int m = 0; m < 4; ++m)
            af[m] = *(const bf16x8*)(&sA[cur][(wr * 64 + m * 16 + lr) * 32 + ((lk ^ sw_rd) << 3)]);
#pragma unroll
        for (int n = 0; n < 4; ++n)
            bg[n] = *(const bf16x8*)(&sB[cur][(wc * 64 + n * 16 + lr) * 32 + ((lk ^ sw_rd) << 3)]);
#pragma unroll
        for (int m = 0; m < 4; ++m)
#pragma unroll
            for (int n = 0; n < 4; ++n)
                acc[m][n] = mfma_bf16(af[m], bg[n], acc[m][n]);
        __syncthreads();   // implicit vmcnt(0): next tile's DMA has landed; cur reusable
    }

#pragma unroll
    for (int n = 0; n < 4; ++n) {
        int col = n0 + wc * 64 + n * 16 + lr;
        float bv = bias[col];
#pragma unroll
        for (int m = 0; m < 4; ++m) {
            int row0 = m0 + wr * 64 + m * 16 + lk * 4;
#pragma unroll
            for (int j = 0; j < 4; ++j) {
                float v = acc[m][n][j] + bv;
                if (OUT_BF16)
                    ((__bf16*)Cout)[(size_t)(row0 + j) * N + col] = (__bf16)v;
                else
                    ((float*)Cout)[(size_t)(row0 + j) * N + col] = v;
            }
        }
    }
}

// ---------------- causal flash attention ----------------
// 768 blocks; block = (pair pr, h, b) handles q-tiles {pr, 15-pr} (uniform 17 tiles).
// 4 waves x 16 q-rows; swapped QK^T (lane owns one q-row -> 2-shuffle softmax).
// K: dbuf LDS via global_load_lds with source-pre-swizzled chunks (linear dest).
// V: dbuf LDS, reg-staged transpose with XOR swizzle. 1 barrier per KV tile.
__global__ __launch_bounds__(256, 2) void attn_fwd(const __bf16* __restrict__ qkv,
                                                   __bf16* __restrict__ y) {
    const int tid = threadIdx.x, l = tid & 63, w = tid >> 6;
    const int lr = l & 15, lk = l >> 4;
    const int r7 = lr & 7;
    const int bid = blockIdx.x;
    // XCD swizzle: all 8 pair-blocks of one (b,h) share bid%8 -> same XCD L2
    const int pr = bid / 96;                 // 0..7
    const int hb = bid % 96;
    const int h = hb % NHEAD;
    const int b = hb / NHEAD;

    __shared__ __align__(16) __bf16 sK[2][64][64];   // chunk-swizzled: phys c = log c ^ (row&7)
    __shared__ __align__(16) __bf16 sV[2][64][64];   // [d][key], XOR-swizzled columns
    __shared__ __align__(16) __bf16 sP[4][16][72];   // per-wave P tile [q][key] (no barrier)

    const size_t baseQ = (size_t)b * T_SEQ * C3 + h * HD;
    const __bf16* Kp = qkv + baseQ + CDIM;
    const __bf16* Vp = qkv + baseQ + 2 * CDIM;

    // V staging geometry: key = i*32 + (tid>>3), d-block = (tid&7)*8
    const int vk0 = tid >> 3;
    const int vc = (tid & 7) << 3;
    const int vg = tid & 7;
    // K staging geometry (gload16): phys slot row = i*32 + (tid>>3), chunk c = tid&7;
    // fetch global chunk c ^ (row&7) so linear DMA lands swizzled.
    const int krow = tid >> 3;               // + i*32 (i*32 % 8 == 0)
    const int kchunk = (tid & 7) ^ ((tid >> 3) & 7);

#pragma unroll 1
    for (int job = 0; job < 2; ++job) {
        const int qt = (job == 0) ? pr : 15 - pr;
        const int q0 = qt * 64;
        const int nt = qt + 1;
        const int q_abs = q0 + w * 16 + lr;

        // Q fragments (regs, whole job)
        const size_t rowQ = baseQ + (size_t)(q0 + w * 16 + lr) * C3;
        bf16x8 qa0 = *(const bf16x8*)(qkv + rowQ + lk * 8);
        bf16x8 qa1 = *(const bf16x8*)(qkv + rowQ + 32 + lk * 8);

        f32x4 acc[4];
#pragma unroll
        for (int fd = 0; fd < 4; ++fd) acc[fd] = f32x4{0.f, 0.f, 0.f, 0.f};
        float mrun = -1e30f, lrun = 0.f;

        bf16x8 vreg[2];
        // ---- prologue: stage K(0), V(0) into buffer 0 ----
#pragma unroll
        for (int i = 0; i < 2; ++i)
            vreg[i] = *(const bf16x8*)(Vp + (size_t)(i * 32 + vk0) * C3 + vc);
#pragma unroll
        for (int i = 0; i < 2; ++i)
            gload16(Kp + (size_t)(i * 32 + krow) * C3 + kchunk * 8,
                    (char*)&sK[0][0][0] + (i * 256 + w * 64) * 16);
#pragma unroll
        for (int i = 0; i < 2; ++i) {
            int key = i * 32 + vk0;
#pragma unroll
            for (int e = 0; e < 8; ++e)
                sV[0][vc + e][key ^ ((e ^ vg) << 3)] = vreg[i][e];
        }
        __syncthreads();   // K DMA + V writes visible (also fences prev job's reads)

#pragma unroll 1
        for (int t = 0; t < nt; ++t) {
            const int kv0 = t * 64;
            const int cur = t & 1, nxt = cur ^ 1;
            const bool pre = (t + 1 < nt);
            // ---- issue next-tile loads first (latency hides under compute) ----
            if (pre) {
                const int kvp = kv0 + 64;
#pragma unroll
                for (int i = 0; i < 2; ++i)
                    vreg[i] = *(const bf16x8*)(Vp + (size_t)(kvp + i * 32 + vk0) * C3 + vc);
#pragma unroll
                for (int i = 0; i < 2; ++i)
                    gload16(Kp + (size_t)(kvp + i * 32 + krow) * C3 + kchunk * 8,
                            (char*)&sK[nxt][0][0] + (i * 256 + w * 64) * 16);
            }
            // ---- S^T = K·Q^T : lane (lr,lk) -> S[q=q0+w*16+lr][key=kv0+fc*16+lk*4+j]
            f32x4 s[4];
#pragma unroll
            for (int fc = 0; fc < 4; ++fc) {
                const __bf16* kr = &sK[cur][fc * 16 + lr][0];
                bf16x8 k0 = *(const bf16x8*)(kr + ((lk ^ r7) << 3));
                bf16x8 k1 = *(const bf16x8*)(kr + (((4 + lk) ^ r7) << 3));
                f32x4 z = f32x4{0.f, 0.f, 0.f, 0.f};
                z = mfma_bf16(k0, qa0, z);
                z = mfma_bf16(k1, qa1, z);
                s[fc] = z;
            }
            // ---- online softmax: per-lane m/l, 2-shuffle reductions ----
            float ps[4][4];
#pragma unroll
            for (int fc = 0; fc < 4; ++fc)
#pragma unroll
                for (int j = 0; j < 4; ++j) {
                    int key = kv0 + fc * 16 + lk * 4 + j;
                    ps[fc][j] = (key <= q_abs) ? s[fc][j] * ATT_SCALE : -1e30f;
                }
            float mt = -1e30f;
#pragma unroll
            for (int fc = 0; fc < 4; ++fc)
#pragma unroll
                for (int j = 0; j < 4; ++j) mt = fmaxf(mt, ps[fc][j]);
            mt = fmaxf(mt, __shfl_xor(mt, 16, 64));
            mt = fmaxf(mt, __shfl_xor(mt, 32, 64));
            const float mn = fmaxf(mrun, mt);
            const float corr = __expf(mrun - mn);
            mrun = mn;
            float rs = 0.f;
#pragma unroll
            for (int fc = 0; fc < 4; ++fc)
#pragma unroll
                for (int j = 0; j < 4; ++j) {
                    float p = __expf(ps[fc][j] - mn);
                    ps[fc][j] = p;
                    rs += p;
                }
            rs += __shfl_xor(rs, 16, 64);
            rs += __shfl_xor(rs, 32, 64);
            lrun = lrun * corr + rs;
            float cj[4];
#pragma unroll
            for (int j = 0; j < 4; ++j) cj[j] = __shfl(corr, lk * 4 + j, 64);
#pragma unroll
            for (int fd = 0; fd < 4; ++fd)
#pragma unroll
                for (int j = 0; j < 4; ++j) acc[fd][j] *= cj[j];
            // ---- P -> sP (per-wave private; paired b32 writes) ----
#pragma unroll
            for (int fc = 0; fc < 4; ++fc)
#pragma unroll
                for (int jp = 0; jp < 2; ++jp) {
                    bf16x2 pk = { (__bf16)ps[fc][jp * 2], (__bf16)ps[fc][jp * 2 + 1] };
                    *(bf16x2*)&sP[w][lr][fc * 16 + lk * 4 + jp * 2] = pk;
                }
            // ---- O += P·V from sV[cur] (swizzled b128 reads) ----
#pragma unroll
            for (int ks = 0; ks < 2; ++ks) {
                bf16x8 pa = *(const bf16x8*)&sP[w][lr][ks * 32 + lk * 8];
#pragma unroll
                for (int fd = 0; fd < 4; ++fd) {
                    int d = fd * 16 + lr;
                    int sw = ((d & 7) ^ ((d >> 3) & 7)) << 3;
                    bf16x8 vb = *(const bf16x8*)&sV[cur][d][(ks * 32 + lk * 8) ^ sw];
                    acc[fd] = mfma_bf16(pa, vb, acc[fd]);
                }
            }
            // ---- stage V(t+1) into sV[nxt] ----
            if (pre) {
#pragma unroll
                for (int i = 0; i < 2; ++i) {
                    int key = i * 32 + vk0;
#pragma unroll
                    for (int e = 0; e < 8; ++e)
                        sV[nxt][vc + e][key ^ ((e ^ vg) << 3)] = vreg[i][e];
                }
            }
            __syncthreads();   // drains K DMA (vmcnt) + V writes for tile t+1
        }

        // ---- epilogue: y[b*T+q][h*64+d], q = q0+w*16+lk*4+j, d = fd*16+lr ----
        float linv[4];
#pragma unroll
        for (int j = 0; j < 4; ++j) linv[j] = 1.f / __shfl(lrun, lk * 4 + j, 64);
        const size_t yrow0 = (size_t)(b * T_SEQ + q0 + w * 16 + lk * 4);
#pragma unroll
        for (int fd = 0; fd < 4; ++fd) {
            int col = h * HD + fd * 16 + lr;
#pragma unroll
            for (int j = 0; j < 4; ++j)
                y[(yrow0 + j) * CDIM + col] = (__bf16)(acc[fd][j] * linv[j]);
        }
    }
}

// ---------------- launch ----------------
extern "C" void kernel_launch(void* const* d_in, const int* in_sizes, int n_in,
                              void* d_out, int out_size, void* d_ws, size_t ws_size,
                              hipStream_t stream) {
    const float* x      = (const float*)d_in[0];
    const float* W_attn = (const float*)d_in[1];
    const float* b_attn = (const float*)d_in[2];
    const float* W_proj = (const float*)d_in[3];
    const float* b_proj = (const float*)d_in[4];

    __bf16* xb  = (__bf16*)d_ws;                       // [8192][768]
    __bf16* Wat = xb  + (size_t)8192 * 768;            // [2304][768]  (W_attn^T)
    __bf16* Wpt = Wat + (size_t)2304 * 768;            // [768][768]   (W_proj^T)
    __bf16* qkv = Wpt + (size_t)768 * 768;             // [8192][2304]
    __bf16* yb  = qkv + (size_t)8192 * 2304;           // [8192][768]

    cvt_f32_bf16<<<6144, 256, 0, stream>>>(x, xb, (8192 * 768) / 4);
    transpose_cvt<<<dim3(72, 24), 256, 0, stream>>>(W_attn, Wat, 768, 2304);
    transpose_cvt<<<dim3(24, 24), 256, 0, stream>>>(W_proj, Wpt, 768, 768);

    gemm_bt<1><<<18 * 64, 256, 0, stream>>>(xb, Wat, b_attn, (void*)qkv, 8192, 2304, 768, 18);
    attn_fwd<<<NBATCH * NHEAD * 8, 256, 0, stream>>>(qkv, yb);
    gemm_bt<0><<<6 * 64, 256, 0, stream>>>(yb, Wpt, b_proj, d_out, 8192, 768, 768, 6);
}

// Round 5
// 118.032 us; speedup vs baseline: 1.9110x; 1.0459x over previous
//
#include <hip/hip_runtime.h>
#include <hip/hip_bf16.h>

// Problem constants (fixed shapes)
#define T_SEQ 1024
#define NBATCH 8
#define NHEAD 12
#define HD 64
#define CDIM 768
#define C3 2304
#define ATT_SCALE 0.125f   // 1/sqrt(64)

typedef __attribute__((ext_vector_type(8))) __bf16 bf16x8;
typedef __attribute__((ext_vector_type(4))) __bf16 bf16x4;
typedef __attribute__((ext_vector_type(2))) __bf16 bf16x2;
typedef __attribute__((ext_vector_type(4))) float  f32x4;

__device__ __forceinline__ f32x4 mfma_bf16(bf16x8 a, bf16x8 b, f32x4 c) {
    return __builtin_amdgcn_mfma_f32_16x16x32_bf16(a, b, c, 0, 0, 0);
}

// async global->LDS, 16B per lane; LDS dest is wave-uniform base (+lane*16 implicit)
__device__ __forceinline__ void gload16(const void* g, void* l) {
    __builtin_amdgcn_global_load_lds(
        (const __attribute__((address_space(1))) unsigned int*)g,
        (__attribute__((address_space(3))) unsigned int*)l, 16, 0, 0);
}

// counted waitcnt + scheduling fence (rule #18)
#define WAIT_VM(N) do { asm volatile("s_waitcnt vmcnt(" #N ")" ::: "memory"); \
                        __builtin_amdgcn_sched_barrier(0); } while (0)
#define WAIT_LGKM0 do { asm volatile("s_waitcnt lgkmcnt(0)" ::: "memory"); \
                        __builtin_amdgcn_sched_barrier(0); } while (0)

// ---------------- f32 -> bf16 convert (vectorized) ----------------
__global__ __launch_bounds__(256) void cvt_f32_bf16(const float* __restrict__ in,
                                                    __bf16* __restrict__ out, int n4) {
    int i = blockIdx.x * 256 + threadIdx.x;
    if (i < n4) {
        float4 v = ((const float4*)in)[i];
        bf16x4 o = { (__bf16)v.x, (__bf16)v.y, (__bf16)v.z, (__bf16)v.w };
        ((bf16x4*)out)[i] = o;
    }
}

// ---------------- transpose + convert: W [R][C] f32 -> Wt [C][R] bf16 ----------------
__global__ __launch_bounds__(256) void transpose_cvt(const float* __restrict__ W,
                                                     __bf16* __restrict__ Wt,
                                                     int R, int C) {
    __shared__ float tile[32][33];
    const int c0 = blockIdx.x * 32, r0 = blockIdx.y * 32;
    const int tc = threadIdx.x & 31, tr = threadIdx.x >> 5;   // tr in 0..7
#pragma unroll
    for (int i = 0; i < 4; ++i)
        tile[tr + i * 8][tc] = W[(size_t)(r0 + tr + i * 8) * C + c0 + tc];
    __syncthreads();
#pragma unroll
    for (int i = 0; i < 4; ++i)
        Wt[(size_t)(c0 + tr + i * 8) * R + r0 + tc] = (__bf16)tile[tc][tr + i * 8];
}

// ---------------- GEMM: C[M][N] = A[M][K] @ Bt[N][K]^T + bias ----------------
// 128x128 tile, BK=32, 4 waves; 3-buffer LDS pipeline with COUNTED vmcnt
// (T4: never drain to 0 in the loop — each tile's DMA has ~3 K-steps to land).
// Per iteration: wait vmcnt(8) (tile t landed) -> barrier -> ds_read buf[cur]
// -> lgkmcnt(0) -> barrier (all waves done reading) -> stage(t+3 into buf[cur])
// -> 16 MFMA. Requires nk >= 3 (nk = 24 here).
template<int OUT_BF16>
__global__ __launch_bounds__(256) void gemm_bt(const __bf16* __restrict__ A,
                                               const __bf16* __restrict__ Bt,
                                               const float* __restrict__ bias,
                                               void* __restrict__ Cout,
                                               int M, int N, int K, int nbx) {
    __shared__ __align__(16) __bf16 sA[3][128 * 32];
    __shared__ __align__(16) __bf16 sB[3][128 * 32];
    const int t = threadIdx.x, l = t & 63, w = t >> 6;
    const int lr = l & 15, lk = l >> 4;
    const int wr = w >> 1, wc = w & 1;
    // XCD swizzle: consecutive swz ids (same XCD) share the A row-panel
    const int q = gridDim.x >> 3;
    const int swz = (blockIdx.x & 7) * q + (blockIdx.x >> 3);
    const int m0 = (swz / nbx) * 128, n0 = (swz % nbx) * 128;

    // staging geometry: idx = i*256+t -> row r=idx>>2, chunk c=idx&3 (16B chunks);
    // fetch global chunk c ^ s(r), s(r)=(r&3)^((r>>2)&3)  [both-sides swizzle]
    const int r_st = t >> 2;                       // + i*64
    const int c_st = t & 3;
    const int sw_st = (r_st & 3) ^ ((r_st >> 2) & 3);
    const int g_off = (c_st ^ sw_st) << 3;         // element offset within row
    const int sw_rd = (lr & 3) ^ ((lr >> 2) & 3);  // read-side swizzle (row = ..+lr)

    f32x4 acc[4][4];
#pragma unroll
    for (int m = 0; m < 4; ++m)
#pragma unroll
        for (int n = 0; n < 4; ++n) acc[m][n] = f32x4{0.f, 0.f, 0.f, 0.f};

    const int nk = K >> 5;

    // prologue: stage tiles 0,1,2 into buffers 0,1,2 (12 vmem ops in flight)
#pragma unroll
    for (int s = 0; s < 3; ++s) {
        const int k0 = s << 5;
#pragma unroll
        for (int i = 0; i < 2; ++i) {
            int r = i * 64 + r_st;
            gload16(A + (size_t)(m0 + r) * K + k0 + g_off,
                    (char*)&sA[s][0] + (i * 256 + w * 64) * 16);
            gload16(Bt + (size_t)(n0 + r) * K + k0 + g_off,
                    (char*)&sB[s][0] + (i * 256 + w * 64) * 16);
        }
    }

    int cur = 0;
    for (int kt = 0; kt < nk; ++kt) {
        // tile kt's 4 DMAs are the oldest outstanding; allow the younger 8 (kt+1,kt+2)
        if (kt + 2 < nk)      WAIT_VM(8);
        else if (kt + 1 < nk) WAIT_VM(4);
        else                  WAIT_VM(0);
        __builtin_amdgcn_s_barrier();          // all waves: tile kt landed in buf[cur]

        bf16x8 af[4], bg[4];
#pragma unroll
        for (int m = 0; m < 4; ++m)
            af[m] = *(const bf16x8*)(&sA[cur][(wr * 64 + m * 16 + lr) * 32 + ((lk ^ sw_rd) << 3)]);
#pragma unroll
        for (int n = 0; n < 4; ++n)
            bg[n] = *(const bf16x8*)(&sB[cur][(wc * 64 + n * 16 + lr) * 32 + ((lk ^ sw_rd) << 3)]);
        WAIT_LGKM0;                            // fragments in regs; buf[cur] free
        __builtin_amdgcn_s_barrier();          // all waves done reading buf[cur]

        // refill buf[cur] with tile kt+3 — lands by iteration kt+3's vmcnt
        if (kt + 3 < nk) {
            const int k0 = (kt + 3) << 5;
#pragma unroll
            for (int i = 0; i < 2; ++i) {
                int r = i * 64 + r_st;
                gload16(A + (size_t)(m0 + r) * K + k0 + g_off,
                        (char*)&sA[cur][0] + (i * 256 + w * 64) * 16);
                gload16(Bt + (size_t)(n0 + r) * K + k0 + g_off,
                        (char*)&sB[cur][0] + (i * 256 + w * 64) * 16);
            }
        }

#pragma unroll
        for (int m = 0; m < 4; ++m)
#pragma unroll
            for (int n = 0; n < 4; ++n)
                acc[m][n] = mfma_bf16(af[m], bg[n], acc[m][n]);

        cur = (cur == 2) ? 0 : cur + 1;
    }

#pragma unroll
    for (int n = 0; n < 4; ++n) {
        int col = n0 + wc * 64 + n * 16 + lr;
        float bv = bias[col];
#pragma unroll
        for (int m = 0; m < 4; ++m) {
            int row0 = m0 + wr * 64 + m * 16 + lk * 4;
#pragma unroll
            for (int j = 0; j < 4; ++j) {
                float v = acc[m][n][j] + bv;
                if (OUT_BF16)
                    ((__bf16*)Cout)[(size_t)(row0 + j) * N + col] = (__bf16)v;
                else
                    ((float*)Cout)[(size_t)(row0 + j) * N + col] = v;
            }
        }
    }
}

// ---------------- causal flash attention ----------------
// 768 blocks; block = (pair pr, h, b) handles q-tiles {pr, 15-pr} (uniform 17 tiles).
// 4 waves x 16 q-rows; swapped QK^T (lane owns one q-row -> 2-shuffle softmax).
// K: dbuf LDS via global_load_lds with source-pre-swizzled chunks (linear dest).
// V: dbuf LDS, reg-staged transpose with XOR swizzle. 1 barrier per KV tile.
__global__ __launch_bounds__(256, 2) void attn_fwd(const __bf16* __restrict__ qkv,
                                                   __bf16* __restrict__ y) {
    const int tid = threadIdx.x, l = tid & 63, w = tid >> 6;
    const int lr = l & 15, lk = l >> 4;
    const int r7 = lr & 7;
    const int bid = blockIdx.x;
    // XCD swizzle: all 8 pair-blocks of one (b,h) share bid%8 -> same XCD L2
    const int pr = bid / 96;                 // 0..7
    const int hb = bid % 96;
    const int h = hb % NHEAD;
    const int b = hb / NHEAD;

    __shared__ __align__(16) __bf16 sK[2][64][64];   // chunk-swizzled: phys c = log c ^ (row&7)
    __shared__ __align__(16) __bf16 sV[2][64][64];   // [d][key], XOR-swizzled columns
    __shared__ __align__(16) __bf16 sP[4][16][72];   // per-wave P tile [q][key] (no barrier)

    const size_t baseQ = (size_t)b * T_SEQ * C3 + h * HD;
    const __bf16* Kp = qkv + baseQ + CDIM;
    const __bf16* Vp = qkv + baseQ + 2 * CDIM;

    // V staging geometry: key = i*32 + (tid>>3), d-block = (tid&7)*8
    const int vk0 = tid >> 3;
    const int vc = (tid & 7) << 3;
    const int vg = tid & 7;
    // K staging geometry (gload16): phys slot row = i*32 + (tid>>3), chunk c = tid&7;
    // fetch global chunk c ^ (row&7) so linear DMA lands swizzled.
    const int krow = tid >> 3;               // + i*32 (i*32 % 8 == 0)
    const int kchunk = (tid & 7) ^ ((tid >> 3) & 7);

#pragma unroll 1
    for (int job = 0; job < 2; ++job) {
        const int qt = (job == 0) ? pr : 15 - pr;
        const int q0 = qt * 64;
        const int nt = qt + 1;
        const int q_abs = q0 + w * 16 + lr;

        // Q fragments (regs, whole job)
        const size_t rowQ = baseQ + (size_t)(q0 + w * 16 + lr) * C3;
        bf16x8 qa0 = *(const bf16x8*)(qkv + rowQ + lk * 8);
        bf16x8 qa1 = *(const bf16x8*)(qkv + rowQ + 32 + lk * 8);

        f32x4 acc[4];
#pragma unroll
        for (int fd = 0; fd < 4; ++fd) acc[fd] = f32x4{0.f, 0.f, 0.f, 0.f};
        float mrun = -1e30f, lrun = 0.f;

        bf16x8 vreg[2];
        // ---- prologue: stage K(0), V(0) into buffer 0 ----
#pragma unroll
        for (int i = 0; i < 2; ++i)
            vreg[i] = *(const bf16x8*)(Vp + (size_t)(i * 32 + vk0) * C3 + vc);
#pragma unroll
        for (int i = 0; i < 2; ++i)
            gload16(Kp + (size_t)(i * 32 + krow) * C3 + kchunk * 8,
                    (char*)&sK[0][0][0] + (i * 256 + w * 64) * 16);
#pragma unroll
        for (int i = 0; i < 2; ++i) {
            int key = i * 32 + vk0;
#pragma unroll
            for (int e = 0; e < 8; ++e)
                sV[0][vc + e][key ^ ((e ^ vg) << 3)] = vreg[i][e];
        }
        __syncthreads();   // K DMA + V writes visible (also fences prev job's reads)

#pragma unroll 1
        for (int t = 0; t < nt; ++t) {
            const int kv0 = t * 64;
            const int cur = t & 1, nxt = cur ^ 1;
            const bool pre = (t + 1 < nt);
            // ---- issue next-tile loads first (latency hides under compute) ----
            if (pre) {
                const int kvp = kv0 + 64;
#pragma unroll
                for (int i = 0; i < 2; ++i)
                    vreg[i] = *(const bf16x8*)(Vp + (size_t)(kvp + i * 32 + vk0) * C3 + vc);
#pragma unroll
                for (int i = 0; i < 2; ++i)
                    gload16(Kp + (size_t)(kvp + i * 32 + krow) * C3 + kchunk * 8,
                            (char*)&sK[nxt][0][0] + (i * 256 + w * 64) * 16);
            }
            // ---- S^T = K·Q^T : lane (lr,lk) -> S[q=q0+w*16+lr][key=kv0+fc*16+lk*4+j]
            f32x4 s[4];
#pragma unroll
            for (int fc = 0; fc < 4; ++fc) {
                const __bf16* kr = &sK[cur][fc * 16 + lr][0];
                bf16x8 k0 = *(const bf16x8*)(kr + ((lk ^ r7) << 3));
                bf16x8 k1 = *(const bf16x8*)(kr + (((4 + lk) ^ r7) << 3));
                f32x4 z = f32x4{0.f, 0.f, 0.f, 0.f};
                z = mfma_bf16(k0, qa0, z);
                z = mfma_bf16(k1, qa1, z);
                s[fc] = z;
            }
            // ---- online softmax: per-lane m/l, 2-shuffle reductions ----
            float ps[4][4];
#pragma unroll
            for (int fc = 0; fc < 4; ++fc)
#pragma unroll
                for (int j = 0; j < 4; ++j) {
                    int key = kv0 + fc * 16 + lk * 4 + j;
                    ps[fc][j] = (key <= q_abs) ? s[fc][j] * ATT_SCALE : -1e30f;
                }
            float mt = -1e30f;
#pragma unroll
            for (int fc = 0; fc < 4; ++fc)
#pragma unroll
                for (int j = 0; j < 4; ++j) mt = fmaxf(mt, ps[fc][j]);
            mt = fmaxf(mt, __shfl_xor(mt, 16, 64));
            mt = fmaxf(mt, __shfl_xor(mt, 32, 64));
            const float mn = fmaxf(mrun, mt);
            const float corr = __expf(mrun - mn);
            mrun = mn;
            float rs = 0.f;
#pragma unroll
            for (int fc = 0; fc < 4; ++fc)
#pragma unroll
                for (int j = 0; j < 4; ++j) {
                    float p = __expf(ps[fc][j] - mn);
                    ps[fc][j] = p;
                    rs += p;
                }
            rs += __shfl_xor(rs, 16, 64);
            rs += __shfl_xor(rs, 32, 64);
            lrun = lrun * corr + rs;
            float cj[4];
#pragma unroll
            for (int j = 0; j < 4; ++j) cj[j] = __shfl(corr, lk * 4 + j, 64);
#pragma unroll
            for (int fd = 0; fd < 4; ++fd)
#pragma unroll
                for (int j = 0; j < 4; ++j) acc[fd][j] *= cj[j];
            // ---- P -> sP (per-wave private; paired b32 writes) ----
#pragma unroll
            for (int fc = 0; fc < 4; ++fc)
#pragma unroll
                for (int jp = 0; jp < 2; ++jp) {
                    bf16x2 pk = { (__bf16)ps[fc][jp * 2], (__bf16)ps[fc][jp * 2 + 1] };
                    *(bf16x2*)&sP[w][lr][fc * 16 + lk * 4 + jp * 2] = pk;
                }
            // ---- O += P·V from sV[cur] (swizzled b128 reads) ----
#pragma unroll
            for (int ks = 0; ks < 2; ++ks) {
                bf16x8 pa = *(const bf16x8*)&sP[w][lr][ks * 32 + lk * 8];
#pragma unroll
                for (int fd = 0; fd < 4; ++fd) {
                    int d = fd * 16 + lr;
                    int sw = ((d & 7) ^ ((d >> 3) & 7)) << 3;
                    bf16x8 vb = *(const bf16x8*)&sV[cur][d][(ks * 32 + lk * 8) ^ sw];
                    acc[fd] = mfma_bf16(pa, vb, acc[fd]);
                }
            }
            // ---- stage V(t+1) into sV[nxt] ----
            if (pre) {
#pragma unroll
                for (int i = 0; i < 2; ++i) {
                    int key = i * 32 + vk0;
#pragma unroll
                    for (int e = 0; e < 8; ++e)
                        sV[nxt][vc + e][key ^ ((e ^ vg) << 3)] = vreg[i][e];
                }
            }
            __syncthreads();   // drains K DMA (vmcnt) + V writes for tile t+1
        }

        // ---- epilogue: y[b*T+q][h*64+d], q = q0+w*16+lk*4+j, d = fd*16+lr ----
        float linv[4];
#pragma unroll
        for (int j = 0; j < 4; ++j) linv[j] = 1.f / __shfl(lrun, lk * 4 + j, 64);
        const size_t yrow0 = (size_t)(b * T_SEQ + q0 + w * 16 + lk * 4);
#pragma unroll
        for (int fd = 0; fd < 4; ++fd) {
            int col = h * HD + fd * 16 + lr;
#pragma unroll
            for (int j = 0; j < 4; ++j)
                y[(yrow0 + j) * CDIM + col] = (__bf16)(acc[fd][j] * linv[j]);
        }
    }
}

// ---------------- launch ----------------
extern "C" void kernel_launch(void* const* d_in, const int* in_sizes, int n_in,
                              void* d_out, int out_size, void* d_ws, size_t ws_size,
                              hipStream_t stream) {
    const float* x      = (const float*)d_in[0];
    const float* W_attn = (const float*)d_in[1];
    const float* b_attn = (const float*)d_in[2];
    const float* W_proj = (const float*)d_in[3];
    const float* b_proj = (const float*)d_in[4];

    __bf16* xb  = (__bf16*)d_ws;                       // [8192][768]
    __bf16* Wat = xb  + (size_t)8192 * 768;            // [2304][768]  (W_attn^T)
    __bf16* Wpt = Wat + (size_t)2304 * 768;            // [768][768]   (W_proj^T)
    __bf16* qkv = Wpt + (size_t)768 * 768;             // [8192][2304]
    __bf16* yb  = qkv + (size_t)8192 * 2304;           // [8192][768]

    cvt_f32_bf16<<<6144, 256, 0, stream>>>(x, xb, (8192 * 768) / 4);
    transpose_cvt<<<dim3(72, 24), 256, 0, stream>>>(W_attn, Wat, 768, 2304);
    transpose_cvt<<<dim3(24, 24), 256, 0, stream>>>(W_proj, Wpt, 768, 768);

    gemm_bt<1><<<18 * 64, 256, 0, stream>>>(xb, Wat, b_attn, (void*)qkv, 8192, 2304, 768, 18);
    attn_fwd<<<NBATCH * NHEAD * 8, 256, 0, stream>>>(qkv, yb);
    gemm_bt<0><<<6 * 64, 256, 0, stream>>>(yb, Wpt, b_proj, d_out, 8192, 768, 768, 6);
}